// Round 9
// baseline (691.951 us; speedup 1.0000x reference)
//
#include <hip/hip_runtime.h>
#include <hip/hip_bf16.h>

#define BB 4
#define CC 512
#define NN 4096
#define DD 64   // C8

typedef __attribute__((ext_vector_type(8))) short short8;
typedef __attribute__((ext_vector_type(4))) short short4v;
typedef __attribute__((ext_vector_type(4))) float floatx4;

static __device__ __forceinline__ short f2bf(float f) {
  __hip_bfloat16 h = __float2bfloat16(f);
  return *reinterpret_cast<short*>(&h);
}

static __device__ __forceinline__ floatx4 mfma16(short8 a, short8 b, floatx4 c) {
  return __builtin_amdgcn_mfma_f32_16x16x32_bf16(a, b, c, 0, 0, 0);
}

#define GLOAD_LDS16(gp, lp) \
  __builtin_amdgcn_global_load_lds((const __attribute__((address_space(1))) void*)(gp), \
                                   (__attribute__((address_space(3))) void*)(lp), 16, 0, 0)

// ---------------------------------------------------------------------------
// Kernel 0: convert W (Wq 0-63, Wk 64-127, Wv 128-639) to bf16 [640][512]
// ---------------------------------------------------------------------------
__global__ void wconv_kernel(const float* __restrict__ Wq, const float* __restrict__ Wk,
                             const float* __restrict__ Wv, short* __restrict__ Wb) {
  int i = blockIdx.x * 256 + threadIdx.x;   // 640*512
  int row = i >> 9, c = i & 511;
  float v;
  if (row < 64)        v = Wq[(row << 9) | c];
  else if (row < 128)  v = Wk[((row - 64) << 9) | c];
  else                 v = Wv[((row - 128) << 9) | c];
  Wb[i] = f2bf(v);
}

// ---------------------------------------------------------------------------
// Kernel 0b: transpose x[b][c][n] f32 -> xT[b][n][c] bf16 (64x64 tiles via LDS)
// xT lives in d_out (scratch; attn overwrites d_out afterwards).
// ---------------------------------------------------------------------------
__global__ __launch_bounds__(256) void txpose_kernel(const float* __restrict__ x,
                                                     short* __restrict__ xT) {
  const int bid = blockIdx.x;           // 4b x 8ct x 64nt
  const int b  = bid >> 9;
  const int ct = (bid >> 6) & 7,  c0 = ct << 6;
  const int nt = bid & 63,        n0 = nt << 6;
  const int tid = threadIdx.x;
  const int tn = (tid & 15) << 2;       // n-offset 0..60
  const int tc = tid >> 4;              // 0..15

  __shared__ short t[64][70];

  const float* xb = x + (size_t)b * CC * NN;
  #pragma unroll
  for (int i = 0; i < 4; ++i) {
    int c = tc + i * 16;
    floatx4 v = *(const floatx4*)(xb + (size_t)(c0 + c) * NN + n0 + tn);
    short4v pk;
    #pragma unroll
    for (int j = 0; j < 4; ++j) pk[j] = f2bf(v[j]);
    *(short4v*)&t[c][tn] = pk;
  }
  __syncthreads();
  #pragma unroll
  for (int i = 0; i < 4; ++i) {
    int n = tc + i * 16;
    short4v pk;
    #pragma unroll
    for (int j = 0; j < 4; ++j) pk[j] = t[tn + j][n];
    *(short4v*)(xT + ((size_t)b * NN + n0 + n) * CC + c0 + tn) = pk;
  }
}

// ---------------------------------------------------------------------------
// Kernel 1: QKV GEMM, LDS-free, barrier-free.
//   C[n][dout] = xT[n][:] . Wb[dout][:] + bias ; M-tile 32 per block.
// grid 512 (b x 128 ntiles), 8 waves; wave owns dout [80w, 80w+80).
// Both operands read as direct-global b128 fragments (L2-resident).
// ---------------------------------------------------------------------------
__global__ __launch_bounds__(512, 4) void qkv_kernel(
    const short* __restrict__ xT, const short* __restrict__ Wb,
    const float* __restrict__ bq, const float* __restrict__ bk,
    const float* __restrict__ bv,
    short* __restrict__ qb, short* __restrict__ kb, short* __restrict__ vb) {
  const int bid = blockIdx.x;
  const int b  = bid >> 7;
  const int n0 = (bid & 127) << 5;
  const int tid = threadIdx.x;
  const int w = tid >> 6, lane = tid & 63;
  const int arow = lane & 15, grp = lane >> 4;

  floatx4 acc[2][5];
  #pragma unroll
  for (int i = 0; i < 2; ++i)
    #pragma unroll
    for (int j = 0; j < 5; ++j) acc[i][j] = (floatx4){0.f, 0.f, 0.f, 0.f};

  const short* aB = xT + ((size_t)b * NN + n0) * CC;
  const short* wB = Wb + (size_t)(w * 80) * CC;

  for (int kk = 0; kk < 8; ++kk) {
    #pragma unroll
    for (int ks = 0; ks < 2; ++ks) {
      const int ko = kk * 64 + ks * 32 + grp * 8;
      short8 af[2];
      #pragma unroll
      for (int ms = 0; ms < 2; ++ms)
        af[ms] = *(const short8*)(aB + (size_t)(ms * 16 + arow) * CC + ko);
      #pragma unroll
      for (int ds = 0; ds < 5; ++ds) {
        short8 wf = *(const short8*)(wB + (size_t)(ds * 16 + arow) * CC + ko);
        #pragma unroll
        for (int ms = 0; ms < 2; ++ms)
          acc[ms][ds] = mfma16(af[ms], wf, acc[ms][ds]);
      }
    }
  }

  #pragma unroll
  for (int ds = 0; ds < 5; ++ds) {
    int dout = w * 80 + ds * 16 + arow;
    float bias = (dout < 64) ? bq[dout] : (dout < 128) ? bk[dout - 64] : bv[dout - 128];
    #pragma unroll
    for (int ms = 0; ms < 2; ++ms) {
      int n = n0 + ms * 16 + grp * 4;
      floatx4 a = acc[ms][ds];
      if (dout < 64) {
        #pragma unroll
        for (int r = 0; r < 4; ++r)
          qb[((size_t)b * NN + n + r) * DD + dout] = f2bf(a[r] + bias);
      } else if (dout < 128) {
        #pragma unroll
        for (int r = 0; r < 4; ++r)
          kb[((size_t)b * NN + n + r) * DD + (dout - 64)] = f2bf(a[r] + bias);
      } else {
        short4v pk;
        #pragma unroll
        for (int r = 0; r < 4; ++r) pk[r] = f2bf(a[r] + bias);
        *(short4v*)(vb + ((size_t)b * CC + (dout - 128)) * NN + n) = pk;
      }
    }
  }
}

// ---------------------------------------------------------------------------
// Kernel 2: fused attention. m-tile 128, c-slice 128 (ch-split 4), n-block 64.
// Single barrier per iteration; vbuf+pbuf double-buffered; v staged via
// chunk-XOR-preswizzled global_load_lds. XCD-pinned: slice = (bid&7) + 8*(slot&1).
// Self-normalizing softmax (no max; denominator in regs).
// ---------------------------------------------------------------------------
__global__ __launch_bounds__(512, 4) void attn_kernel(
    const short* __restrict__ qb, const short* __restrict__ kb,
    const short* __restrict__ vb, const float* __restrict__ x,
    const float* __restrict__ gamma, float* __restrict__ out) {
  const int bid = blockIdx.x;
  const int xcd = bid & 7;
  const int slot = bid >> 3;              // 0..63
  const int slice = xcd + 8 * (slot & 1); // 0..15
  const int b = slice >> 2, ch = slice & 3;
  const int m0 = (slot >> 1) << 7;        // 32 m-tiles of 128
  const int tid = threadIdx.x;
  const int w = tid >> 6, lane = tid & 63;
  const int arow = lane & 15, grp = lane >> 4;
  const int nsub = w & 3;    // P1: n-subtile
  const int mh = w >> 2;     // m-half (64 rows)
  const int wc = w & 3;      // PV: c 32-slice

  __shared__ short vbuf[2][128 * 64];   // 32 KB: v[c128][n64 swizzled]
  __shared__ short pbuf[2][128 * 64];   // 32 KB: P[m128][n64 swizzled]
  __shared__ float dsum[4][128];

  const short* qB = qb + (size_t)b * NN * DD;
  const short* kB = kb + (size_t)b * NN * DD;
  const short* vB = vb + ((size_t)b * CC + ch * 128) * NN;

  const int dma_row = lane >> 3;
  const int dma_nsw = ((lane & 7) ^ dma_row) << 3;

  // hoisted k fragments: wave's m-half = 4 subtiles of 16
  short8 afr[4][2];
  #pragma unroll
  for (int h = 0; h < 4; ++h) {
    const short* kr = kB + (size_t)(m0 + mh * 64 + h * 16 + arow) * DD;
    afr[h][0] = *(const short8*)(kr + grp * 8);
    afr[h][1] = *(const short8*)(kr + 32 + grp * 8);
  }

  floatx4 acc[4][2];   // [ms][cs]
  #pragma unroll
  for (int i = 0; i < 4; ++i)
    #pragma unroll
    for (int j = 0; j < 2; ++j) acc[i][j] = (floatx4){0.f, 0.f, 0.f, 0.f};
  float dl[4][4];
  #pragma unroll
  for (int h = 0; h < 4; ++h)
    #pragma unroll
    for (int r = 0; r < 4; ++r) dl[h][r] = 0.f;

  short8 qa0, qa1;
  {
    const short* qr = qB + (size_t)(nsub * 16 + arow) * DD + grp * 8;
    qa0 = *(const short8*)(qr);
    qa1 = *(const short8*)(qr + 32);
  }

  // ---- prologue: DMA v(0); P1(0)->pbuf[0]; qa(1) ----
  #pragma unroll
  for (int q2 = 0; q2 < 2; ++q2)
    GLOAD_LDS16(vB + (size_t)(w * 16 + q2 * 8 + dma_row) * NN + dma_nsw,
                &vbuf[0][(w * 16 + q2 * 8) * 64]);
  #pragma unroll
  for (int h = 0; h < 4; ++h) {
    floatx4 s4 = (floatx4){0.f, 0.f, 0.f, 0.f};
    s4 = mfma16(afr[h][0], qa0, s4);
    s4 = mfma16(afr[h][1], qa1, s4);
    int mrow = mh * 64 + h * 16 + grp * 4;
    #pragma unroll
    for (int r = 0; r < 4; ++r) {
      float p = __expf(s4[r]);
      dl[h][r] += p;
      int row = mrow + r;
      pbuf[0][row * 64 + ((nsub * 16 + arow) ^ ((row & 7) << 3))] = f2bf(p);
    }
  }
  {
    const short* qr = qB + (size_t)(64 + nsub * 16 + arow) * DD + grp * 8;
    qa0 = *(const short8*)(qr);
    qa1 = *(const short8*)(qr + 32);
  }
  __syncthreads();

  for (int i = 0; i < 64; ++i) {
    const int cur = i & 1, nxt = cur ^ 1;
    if (i < 63) {
      const int nb1 = (i + 1) << 6;
      // DMA v(i+1) -> vbuf[nxt]  (latency hides under P1 + PV below)
      #pragma unroll
      for (int q2 = 0; q2 < 2; ++q2)
        GLOAD_LDS16(vB + (size_t)(w * 16 + q2 * 8 + dma_row) * NN + nb1 + dma_nsw,
                    &vbuf[nxt][(w * 16 + q2 * 8) * 64]);
      // P1(i+1) -> pbuf[nxt]
      #pragma unroll
      for (int h = 0; h < 4; ++h) {
        floatx4 s4 = (floatx4){0.f, 0.f, 0.f, 0.f};
        s4 = mfma16(afr[h][0], qa0, s4);
        s4 = mfma16(afr[h][1], qa1, s4);
        int mrow = mh * 64 + h * 16 + grp * 4;
        #pragma unroll
        for (int r = 0; r < 4; ++r) {
          float p = __expf(s4[r]);
          dl[h][r] += p;
          int row = mrow + r;
          pbuf[nxt][row * 64 + ((nsub * 16 + arow) ^ ((row & 7) << 3))] = f2bf(p);
        }
      }
      if (i < 62) {
        const short* qr = qB + (size_t)(((i + 2) << 6) + nsub * 16 + arow) * DD + grp * 8;
        qa0 = *(const short8*)(qr);
        qa1 = *(const short8*)(qr + 32);
      }
    }
    // ---- PV(i): pbuf[cur] x vbuf[cur], 16 MFMA ----
    {
      short8 pa[4][2];
      #pragma unroll
      for (int ms = 0; ms < 4; ++ms) {
        int row = mh * 64 + ms * 16 + arow;
        #pragma unroll
        for (int ks = 0; ks < 2; ++ks)
          pa[ms][ks] = *(const short8*)&pbuf[cur][row * 64 +
                          ((ks * 32 + grp * 8) ^ ((arow & 7) << 3))];
      }
      short8 vv[2][2];
      #pragma unroll
      for (int cs = 0; cs < 2; ++cs) {
        int vb0 = (wc * 32 + cs * 16 + arow) * 64 + ((grp ^ (arow & 7)) << 3);
        vv[cs][0] = *(const short8*)&vbuf[cur][vb0];
        vv[cs][1] = *(const short8*)&vbuf[cur][vb0 ^ 32];
      }
      __builtin_amdgcn_s_setprio(1);
      #pragma unroll
      for (int ks = 0; ks < 2; ++ks)
        #pragma unroll
        for (int cs = 0; cs < 2; ++cs)
          #pragma unroll
          for (int ms = 0; ms < 4; ++ms)
            acc[ms][cs] = mfma16(pa[ms][ks], vv[cs][ks], acc[ms][cs]);
      __builtin_amdgcn_s_setprio(0);
    }
    __syncthreads();   // pbuf[nxt]/vbuf[nxt] ready; all reads of [cur] done
  }

  // denominator: reduce over 16 arow lanes; combine 4 nsub partials via LDS
  #pragma unroll
  for (int off = 1; off < 16; off <<= 1)
    #pragma unroll
    for (int h = 0; h < 4; ++h)
      #pragma unroll
      for (int r = 0; r < 4; ++r)
        dl[h][r] += __shfl_xor(dl[h][r], off);
  if (arow == 0) {
    #pragma unroll
    for (int h = 0; h < 4; ++h)
      #pragma unroll
      for (int r = 0; r < 4; ++r)
        dsum[nsub][mh * 64 + h * 16 + grp * 4 + r] = dl[h][r];
  }
  __syncthreads();

  const float g = *gamma;
  #pragma unroll
  for (int ms = 0; ms < 4; ++ms) {
    int ml = mh * 64 + ms * 16 + grp * 4;
    floatx4 linv;
    #pragma unroll
    for (int r = 0; r < 4; ++r) {
      float l = dsum[0][ml + r] + dsum[1][ml + r] + dsum[2][ml + r] + dsum[3][ml + r];
      linv[r] = g / l;
    }
    #pragma unroll
    for (int cs = 0; cs < 2; ++cs) {
      int c = ch * 128 + wc * 32 + cs * 16 + arow;
      const float* xp = x + ((size_t)b * CC + c) * NN + m0 + ml;
      floatx4 xv = *(const floatx4*)xp;
      floatx4 res;
      #pragma unroll
      for (int r = 0; r < 4; ++r) res[r] = acc[ms][cs][r] * linv[r] + xv[r];
      *(floatx4*)(out + ((size_t)b * CC + c) * NN + m0 + ml) = res;
    }
  }
}

// ---------------------------------------------------------------------------
extern "C" void kernel_launch(void* const* d_in, const int* in_sizes, int n_in,
                              void* d_out, int out_size, void* d_ws, size_t ws_size,
                              hipStream_t stream) {
  const float* x     = (const float*)d_in[0];
  const float* Wq    = (const float*)d_in[1];
  const float* bq    = (const float*)d_in[2];
  const float* Wk    = (const float*)d_in[3];
  const float* bk    = (const float*)d_in[4];
  const float* Wv    = (const float*)d_in[5];
  const float* bv    = (const float*)d_in[6];
  const float* gamma = (const float*)d_in[7];
  float* out = (float*)d_out;

  char* ws = (char*)d_ws;
  short* qb = (short*)(ws);                // 2 MB
  short* kb = (short*)(ws + (2u << 20));   // 2 MB
  short* vb = (short*)(ws + (4u << 20));   // 16 MB
  short* Wb = (short*)(ws + (21u << 20));  // 640 KB
  short* xT = (short*)d_out;               // 16.8 MB scratch; attn overwrites out

  hipLaunchKernelGGL(wconv_kernel, dim3(1280), dim3(256), 0, stream, Wq, Wk, Wv, Wb);
  hipLaunchKernelGGL(txpose_kernel, dim3(4 * 8 * 64), dim3(256), 0, stream, x, xT);
  hipLaunchKernelGGL(qkv_kernel, dim3(512), dim3(512), 0, stream,
                     xT, Wb, bq, bk, bv, qb, kb, vb);
  hipLaunchKernelGGL(attn_kernel, dim3(512), dim3(512), 0, stream,
                     qb, kb, vb, x, gamma, out);
}

// Round 11
// 391.818 us; speedup vs baseline: 1.7660x; 1.7660x over previous
//
#include <hip/hip_runtime.h>
#include <hip/hip_bf16.h>

#define BB 4
#define CC 512
#define NN 4096
#define DD 64   // C8

typedef __attribute__((ext_vector_type(8))) short short8;
typedef __attribute__((ext_vector_type(4))) short short4v;
typedef __attribute__((ext_vector_type(4))) float floatx4;

static __device__ __forceinline__ short f2bf(float f) {
  __hip_bfloat16 h = __float2bfloat16(f);
  return *reinterpret_cast<short*>(&h);
}

static __device__ __forceinline__ floatx4 mfma16(short8 a, short8 b, floatx4 c) {
  return __builtin_amdgcn_mfma_f32_16x16x32_bf16(a, b, c, 0, 0, 0);
}

#define GLOAD_LDS16(gp, lp) \
  __builtin_amdgcn_global_load_lds((const __attribute__((address_space(1))) void*)(gp), \
                                   (__attribute__((address_space(3))) void*)(lp), 16, 0, 0)

// ---------------------------------------------------------------------------
// Kernel 0: convert W (Wq 0-63, Wk 64-127, Wv 128-639) to bf16 [640][512]
// ---------------------------------------------------------------------------
__global__ void wconv_kernel(const float* __restrict__ Wq, const float* __restrict__ Wk,
                             const float* __restrict__ Wv, short* __restrict__ Wb) {
  int i = blockIdx.x * 256 + threadIdx.x;   // 640*512
  int row = i >> 9, c = i & 511;
  float v;
  if (row < 64)        v = Wq[(row << 9) | c];
  else if (row < 128)  v = Wk[((row - 64) << 9) | c];
  else                 v = Wv[((row - 128) << 9) | c];
  Wb[i] = f2bf(v);
}

// ---------------------------------------------------------------------------
// Kernel 1: QKV as 128x128-tile GEMM (round-8 version, measured good).
// ---------------------------------------------------------------------------
__global__ __launch_bounds__(512, 4) void qkv_kernel(
    const float* __restrict__ x, const short* __restrict__ Wb,
    const float* __restrict__ bq, const float* __restrict__ bk,
    const float* __restrict__ bv,
    short* __restrict__ qb, short* __restrict__ kb, short* __restrict__ vb) {
  const int bid = blockIdx.x;
  const int jt = bid % 5;
  const int mt = bid / 5;
  const int b  = mt >> 5;
  const int n0 = (mt & 31) << 7;
  const int tid = threadIdx.x;
  const int w = tid >> 6, lane = tid & 63;
  const int arow = lane & 15, grp = lane >> 4;
  const int wm = w >> 2, wj = w & 3;

  __shared__ short xs[128][72];   // [m][k], +8 pad

  const float* xb = x + (size_t)b * CC * NN;
  const int n4l = (tid & 31) << 2;
  const int c4  = (tid >> 5) << 2;

  floatx4 ld[4];
  #pragma unroll
  for (int i = 0; i < 4; ++i)
    ld[i] = *(const floatx4*)(xb + (size_t)(c4 + i) * NN + n0 + n4l);

  floatx4 acc[4][2];
  #pragma unroll
  for (int i = 0; i < 4; ++i)
    #pragma unroll
    for (int j = 0; j < 2; ++j) acc[i][j] = (floatx4){0.f, 0.f, 0.f, 0.f};

  for (int kk = 0; kk < 8; ++kk) {
    __syncthreads();
    #pragma unroll
    for (int j = 0; j < 4; ++j) {
      short4v pk;
      #pragma unroll
      for (int i = 0; i < 4; ++i) pk[i] = f2bf(ld[i][j]);
      *(short4v*)&xs[n4l + j][c4] = pk;
    }
    __syncthreads();
    if (kk < 7) {
      #pragma unroll
      for (int i = 0; i < 4; ++i)
        ld[i] = *(const floatx4*)(xb + (size_t)((kk + 1) * 64 + c4 + i) * NN + n0 + n4l);
    }
    #pragma unroll
    for (int ks = 0; ks < 2; ++ks) {
      short8 pa[4];
      #pragma unroll
      for (int ms = 0; ms < 4; ++ms)
        pa[ms] = *(const short8*)&xs[wm * 64 + ms * 16 + arow][ks * 32 + grp * 8];
      #pragma unroll
      for (int js = 0; js < 2; ++js) {
        const short* wp = Wb + (size_t)(jt * 128 + wj * 32 + js * 16 + arow) * CC
                        + kk * 64 + ks * 32 + grp * 8;
        short8 bfr = *(const short8*)wp;
        #pragma unroll
        for (int ms = 0; ms < 4; ++ms)
          acc[ms][js] = mfma16(pa[ms], bfr, acc[ms][js]);
      }
    }
  }

  #pragma unroll
  for (int js = 0; js < 2; ++js) {
    int dout = jt * 128 + wj * 32 + js * 16 + arow;
    float bias = (dout < 64) ? bq[dout] : (dout < 128) ? bk[dout - 64] : bv[dout - 128];
    #pragma unroll
    for (int ms = 0; ms < 4; ++ms) {
      int n = n0 + wm * 64 + ms * 16 + grp * 4;
      floatx4 a = acc[ms][js];
      if (dout < 64) {
        #pragma unroll
        for (int r = 0; r < 4; ++r)
          qb[((size_t)b * NN + n + r) * DD + dout] = f2bf(a[r] + bias);
      } else if (dout < 128) {
        #pragma unroll
        for (int r = 0; r < 4; ++r)
          kb[((size_t)b * NN + n + r) * DD + (dout - 64)] = f2bf(a[r] + bias);
      } else {
        short4v pk;
        #pragma unroll
        for (int r = 0; r < 4; ++r) pk[r] = f2bf(a[r] + bias);
        *(short4v*)(vb + ((size_t)b * CC + (dout - 128)) * NN + n) = pk;
      }
    }
  }
}

// ---------------------------------------------------------------------------
// Kernel 2: fused attention. Round-8 XCD mapping (one (b,ch) slice per XCD,
// m-tile 64, 256-c slice) + single-barrier double-buffered pipeline:
//   iter i: DMA v(i+1)->vbuf[nxt]; P1(i+1)->pbuf[nxt]; PV(i) from [cur]; BAR.
// DMA latency is covered by P1+PV (~2000 cyc). v staged via chunk-XOR
// pre-swizzled global_load_lds; pbuf row-XOR swizzled. Self-normalizing
// softmax (denominator in regs). LDS 80 KB -> 2 blocks/CU.
// ---------------------------------------------------------------------------
__global__ __launch_bounds__(512, 4) void attn_kernel(
    const short* __restrict__ qb, const short* __restrict__ kb,
    const short* __restrict__ vb, const float* __restrict__ x,
    const float* __restrict__ gamma, float* __restrict__ out) {
  const int bid = blockIdx.x;
  const int xcd = bid & 7;
  const int b = xcd >> 1, ch = xcd & 1;
  const int m0 = (bid >> 3) << 6;
  const int tid = threadIdx.x;
  const int w = tid >> 6, lane = tid & 63;
  const int arow = lane & 15, grp = lane >> 4;
  const int nsub = w & 3;    // P1: n-subtile
  const int mh = w >> 2;     // m-half (32 rows)
  const int wc = w & 3;      // PV: c-quarter (64 ch)

  __shared__ __align__(16) char smem[81920];
  short* vbufA = (short*)smem;                     // 2 x 16384 shorts (32 KB each)
  short* pbufA = (short*)(smem + 65536);           // 2 x 4096 shorts (8 KB each)
  float* dsum  = (float*)(smem + 65536);           // [4][64], used only after loop

  const short* qB = qb + (size_t)b * NN * DD;
  const short* kB = kb + (size_t)b * NN * DD;
  const short* vB = vb + ((size_t)b * CC + ch * 256) * NN;

  const int dma_row = lane >> 3;                    // 0..7
  const int dma_nsw = ((lane & 7) ^ dma_row) << 3;  // swizzled n-offset (shorts)

  // hoisted k fragments for this wave's two m-subtiles
  short8 afr[2][2];
  #pragma unroll
  for (int h = 0; h < 2; ++h) {
    const short* kr = kB + (size_t)(m0 + mh * 32 + h * 16 + arow) * DD;
    afr[h][0] = *(const short8*)(kr + grp * 8);
    afr[h][1] = *(const short8*)(kr + 32 + grp * 8);
  }

  floatx4 acc[2][4];   // [ms][cs]
  #pragma unroll
  for (int i = 0; i < 2; ++i)
    #pragma unroll
    for (int j = 0; j < 4; ++j) acc[i][j] = (floatx4){0.f, 0.f, 0.f, 0.f};
  float dl[2][4];
  #pragma unroll
  for (int h = 0; h < 2; ++h)
    #pragma unroll
    for (int r = 0; r < 4; ++r) dl[h][r] = 0.f;

  short8 qa0, qa1;
  {
    const short* qr = qB + (size_t)(nsub * 16 + arow) * DD + grp * 8;
    qa0 = *(const short8*)(qr);
    qa1 = *(const short8*)(qr + 32);
  }

  // ---- prologue: DMA v(0) -> vbuf[0]; P1(0) -> pbuf[0]; qa(1) ----
  #pragma unroll
  for (int q = 0; q < 4; ++q)
    GLOAD_LDS16(vB + (size_t)(w * 32 + q * 8 + dma_row) * NN + dma_nsw,
                vbufA + (w * 32 + q * 8) * 64);
  #pragma unroll
  for (int h = 0; h < 2; ++h) {
    floatx4 s4 = (floatx4){0.f, 0.f, 0.f, 0.f};
    s4 = mfma16(afr[h][0], qa0, s4);
    s4 = mfma16(afr[h][1], qa1, s4);
    int mrow = mh * 32 + h * 16 + grp * 4;
    #pragma unroll
    for (int r = 0; r < 4; ++r) {
      float p = __expf(s4[r]);
      dl[h][r] += p;
      int row = mrow + r;
      pbufA[row * 64 + ((nsub * 16 + arow) ^ ((row & 7) << 3))] = f2bf(p);
    }
  }
  {
    const short* qr = qB + (size_t)(64 + nsub * 16 + arow) * DD + grp * 8;
    qa0 = *(const short8*)(qr);
    qa1 = *(const short8*)(qr + 32);
  }
  __syncthreads();

  for (int i = 0; i < 64; ++i) {
    const int cur = i & 1, nxt = cur ^ 1;
    short* vcur = vbufA + cur * 16384;
    short* vnxt = vbufA + nxt * 16384;
    short* pcur = pbufA + cur * 4096;
    short* pnxt = pbufA + nxt * 4096;
    if (i < 63) {
      const int nb1 = (i + 1) << 6;
      // DMA v(i+1) first: latency hides under P1 + PV below
      #pragma unroll
      for (int q = 0; q < 4; ++q)
        GLOAD_LDS16(vB + (size_t)(w * 32 + q * 8 + dma_row) * NN + nb1 + dma_nsw,
                    vnxt + (w * 32 + q * 8) * 64);
      // P1(i+1) -> pbuf[nxt]
      #pragma unroll
      for (int h = 0; h < 2; ++h) {
        floatx4 s4 = (floatx4){0.f, 0.f, 0.f, 0.f};
        s4 = mfma16(afr[h][0], qa0, s4);
        s4 = mfma16(afr[h][1], qa1, s4);
        int mrow = mh * 32 + h * 16 + grp * 4;
        #pragma unroll
        for (int r = 0; r < 4; ++r) {
          float p = __expf(s4[r]);
          dl[h][r] += p;
          int row = mrow + r;
          pnxt[row * 64 + ((nsub * 16 + arow) ^ ((row & 7) << 3))] = f2bf(p);
        }
      }
      if (i < 62) {
        const short* qr = qB + (size_t)(((i + 2) << 6) + nsub * 16 + arow) * DD + grp * 8;
        qa0 = *(const short8*)(qr);
        qa1 = *(const short8*)(qr + 32);
      }
    }
    // ---- PV(i): pbuf[cur] x vbuf[cur], 16 MFMA ----
    {
      short8 pa[2][2];
      #pragma unroll
      for (int ms = 0; ms < 2; ++ms) {
        int row = mh * 32 + ms * 16 + arow;
        #pragma unroll
        for (int ks = 0; ks < 2; ++ks)
          pa[ms][ks] = *(const short8*)&pcur[row * 64 +
                          ((ks * 32 + grp * 8) ^ ((row & 7) << 3))];
      }
      short8 vv[4][2];
      #pragma unroll
      for (int cs = 0; cs < 4; ++cs) {
        int vb0 = (wc * 64 + cs * 16 + arow) * 64 + ((grp ^ (arow & 7)) << 3);
        vv[cs][0] = *(const short8*)&vcur[vb0];
        vv[cs][1] = *(const short8*)&vcur[vb0 ^ 32];
      }
      __builtin_amdgcn_s_setprio(1);
      #pragma unroll
      for (int ks = 0; ks < 2; ++ks)
        #pragma unroll
        for (int cs = 0; cs < 4; ++cs)
          #pragma unroll
          for (int ms = 0; ms < 2; ++ms)
            acc[ms][cs] = mfma16(pa[ms][ks], vv[cs][ks], acc[ms][cs]);
      __builtin_amdgcn_s_setprio(0);
    }
    __syncthreads();   // v(i+1) landed, P(i+1) visible, reads of [cur] done
  }

  // denominator: reduce dl over 16 arow lanes; combine 4 nsub partials
  #pragma unroll
  for (int off = 1; off < 16; off <<= 1)
    #pragma unroll
    for (int h = 0; h < 2; ++h)
      #pragma unroll
      for (int r = 0; r < 4; ++r)
        dl[h][r] += __shfl_xor(dl[h][r], off);
  if (arow == 0) {
    #pragma unroll
    for (int h = 0; h < 2; ++h)
      #pragma unroll
      for (int r = 0; r < 4; ++r)
        dsum[nsub * 64 + mh * 32 + h * 16 + grp * 4 + r] = dl[h][r];
  }
  __syncthreads();

  const float g = *gamma;
  #pragma unroll
  for (int ms = 0; ms < 2; ++ms) {
    int ml = mh * 32 + ms * 16 + grp * 4;
    floatx4 linv;
    #pragma unroll
    for (int r = 0; r < 4; ++r) {
      float l = dsum[0 * 64 + ml + r] + dsum[1 * 64 + ml + r]
              + dsum[2 * 64 + ml + r] + dsum[3 * 64 + ml + r];
      linv[r] = g / l;
    }
    #pragma unroll
    for (int cs = 0; cs < 4; ++cs) {
      int c = ch * 256 + wc * 64 + cs * 16 + arow;
      const float* xp = x + ((size_t)b * CC + c) * NN + m0 + ml;
      floatx4 xv = *(const floatx4*)xp;
      floatx4 res;
      #pragma unroll
      for (int r = 0; r < 4; ++r) res[r] = acc[ms][cs][r] * linv[r] + xv[r];
      *(floatx4*)(out + ((size_t)b * CC + c) * NN + m0 + ml) = res;
    }
  }
}

// ---------------------------------------------------------------------------
extern "C" void kernel_launch(void* const* d_in, const int* in_sizes, int n_in,
                              void* d_out, int out_size, void* d_ws, size_t ws_size,
                              hipStream_t stream) {
  const float* x     = (const float*)d_in[0];
  const float* Wq    = (const float*)d_in[1];
  const float* bq    = (const float*)d_in[2];
  const float* Wk    = (const float*)d_in[3];
  const float* bk    = (const float*)d_in[4];
  const float* Wv    = (const float*)d_in[5];
  const float* bv    = (const float*)d_in[6];
  const float* gamma = (const float*)d_in[7];
  float* out = (float*)d_out;

  char* ws = (char*)d_ws;
  short* qb = (short*)(ws);                // 2 MB
  short* kb = (short*)(ws + (2u << 20));   // 2 MB
  short* vb = (short*)(ws + (4u << 20));   // 16 MB
  short* Wb = (short*)(ws + (21u << 20));  // 640 KB

  hipLaunchKernelGGL(wconv_kernel, dim3(1280), dim3(256), 0, stream, Wq, Wk, Wv, Wb);
  hipLaunchKernelGGL(qkv_kernel, dim3(640), dim3(512), 0, stream,
                     x, Wb, bq, bk, bv, qb, kb, vb);
  hipLaunchKernelGGL(attn_kernel, dim3(512), dim3(512), 0, stream,
                     qb, kb, vb, x, gamma, out);
}